// Round 8
// baseline (421.073 us; speedup 1.0000x reference)
//
#include <hip/hip_runtime.h>
#include <hip/hip_bf16.h>
#include <hip/hip_cooperative_groups.h>

namespace cg = cooperative_groups;

#define NROWS 8192
#define DDIM  256
#define INV_TEMP 20.0f   // 1/0.05

typedef __attribute__((ext_vector_type(8))) short bf16x8;
typedef __attribute__((ext_vector_type(4))) float f32x4;

// async global->LDS, 16B per lane. LDS dest = uniform base + lane*16.
__device__ static inline void async16(const void* g, void* l) {
    __builtin_amdgcn_global_load_lds(
        (const __attribute__((address_space(1))) void*)g,
        (__attribute__((address_space(3))) void*)l, 16, 0, 0);
}

// ---------------------------------------------------------------------------
// Single cooperative kernel: 256 blocks x 512 threads (8 waves), 96 KB LDS
// -> exactly 1 block/CU, guaranteed co-resident (hipLaunchCooperativeKernel).
// Eliminates 2-3 inter-dispatch gaps (~40-60 us measured across R0-R7).
//
// Phase 1: block b L2-normalizes rows [b*32, b*32+32) of q AND p (4 rows per
//          wave), emits bf16 qn/pn + fp32 diag.
// Phase 2: 4 sequential 256x256 GEMM+sum-exp tiles per block, R6 pipeline
//          verbatim (3 LDS buffers, depth-2 prefetch, counted vmcnt(4)).
//          Persistent mapping: rowblk fixed per block (XCD-chunked),
//          colblk = colgrp*4 + t -> per-XCD hot set ~1.5 MB (L2-fit).
// Phase 3: block b sums its 32 rows across 32 colblocks, logf - diag,
//          block partial -> loss_part[b].
// Phase 4: block 0 reduces 256 partials -> out.
//
// Cross-XCD handoffs: __threadfence() (agent acq_rel: L2 wb/inv per gfx94x+
// memory model) around each grid.sync(). All inter-phase buffers are
// first-touch within this kernel (L2s invalidated at kernel boundary), so
// no stale-line hazard. No O(grid) atomics anywhere (R4 lesson).
// ---------------------------------------------------------------------------
__global__ __launch_bounds__(512, 2) void simcse_fused_kernel(
    const float* __restrict__ q, const float* __restrict__ p,
    unsigned short* __restrict__ qn, unsigned short* __restrict__ pn,
    float* __restrict__ diag,
    float* __restrict__ part,        // [32 colblocks][8192 rows]
    float* __restrict__ loss_part,   // [256]
    float* __restrict__ out)
{
    __shared__ unsigned char lds[3 * 32768];   // 3 x (As 16KB | Bs 16KB)
    cg::grid_group grid = cg::this_grid();

    const int b    = blockIdx.x;      // 0..255
    const int tid  = threadIdx.x;
    const int lane = tid & 63;
    const int w    = tid >> 6;        // wave 0..7

    // ================= Phase 1: normalize 32 rows of q and p ==============
    #pragma unroll 1
    for (int k = 0; k < 4; ++k) {
        const int row = b * 32 + w * 4 + k;

        const float4 qv = ((const float4*)(q + (size_t)row * DDIM))[lane];
        const float4 pv = ((const float4*)(p + (size_t)row * DDIM))[lane];

        float sq = qv.x*qv.x + qv.y*qv.y + qv.z*qv.z + qv.w*qv.w;
        float sp = pv.x*pv.x + pv.y*pv.y + pv.z*pv.z + pv.w*pv.w;
        #pragma unroll
        for (int m = 1; m < 64; m <<= 1) {
            sq += __shfl_xor(sq, m);
            sp += __shfl_xor(sp, m);
        }
        const float qs = 1.0f / fmaxf(sqrtf(sq), 1e-8f);
        const float ps = 1.0f / fmaxf(sqrtf(sp), 1e-8f);

        const float qx = qv.x*qs, qy = qv.y*qs, qz = qv.z*qs, qw = qv.w*qs;
        const float px = pv.x*ps, py = pv.y*ps, pz = pv.z*ps, pw = pv.w*ps;

        float d = qx*px + qy*py + qz*pz + qw*pw;
        #pragma unroll
        for (int m = 1; m < 64; m <<= 1) d += __shfl_xor(d, m);
        if (lane == 0) diag[row] = d * INV_TEMP;

        union { unsigned short u16[4]; uint2 v; } uq, up;
        {
            __hip_bfloat16 bb;
            bb = __float2bfloat16(qx); uq.u16[0] = *(unsigned short*)&bb;
            bb = __float2bfloat16(qy); uq.u16[1] = *(unsigned short*)&bb;
            bb = __float2bfloat16(qz); uq.u16[2] = *(unsigned short*)&bb;
            bb = __float2bfloat16(qw); uq.u16[3] = *(unsigned short*)&bb;
            bb = __float2bfloat16(px); up.u16[0] = *(unsigned short*)&bb;
            bb = __float2bfloat16(py); up.u16[1] = *(unsigned short*)&bb;
            bb = __float2bfloat16(pz); up.u16[2] = *(unsigned short*)&bb;
            bb = __float2bfloat16(pw); up.u16[3] = *(unsigned short*)&bb;
        }
        *(uint2*)(qn + (size_t)row * DDIM + lane * 4) = uq.v;
        *(uint2*)(pn + (size_t)row * DDIM + lane * 4) = up.v;
    }

    __threadfence();
    grid.sync();
    __threadfence();

    // ================= Phase 2: 4 GEMM + sum-exp tiles ====================
    const int wr   = w >> 2;          // wave row (0..1): 128 rows
    const int wc   = w & 3;           // wave col (0..3): 64 cols
    const int quad = lane >> 4;
    const int l16  = lane & 15;

    const int xcd    = b & 7;         // round-robin XCD under dispatch
    const int ii     = b >> 3;        // 0..31 within XCD
    const int rowblk = xcd * 4 + (ii & 3);   // fixed per block
    const int colgrp = ii >> 2;               // 0..7
    const int rowbase = rowblk * 256;

    const unsigned short* gA0 = qn + (size_t)(rowbase + (2*w  )*16 + l16) * DDIM + quad * 8;
    const unsigned short* gA1 = qn + (size_t)(rowbase + (2*w+1)*16 + l16) * DDIM + quad * 8;

    f32x4 acc[8][4];

    #pragma unroll 1
    for (int t = 0; t < 4; ++t) {
        const int colblk  = colgrp * 4 + t;
        const int colbase = colblk * 256;

        const unsigned short* gB0 = pn + (size_t)(colbase + (2*w  )*16 + l16) * DDIM + quad * 8;
        const unsigned short* gB1 = pn + (size_t)(colbase + (2*w+1)*16 + l16) * DDIM + quad * 8;

        #pragma unroll
        for (int i = 0; i < 8; ++i)
            #pragma unroll
            for (int j = 0; j < 4; ++j) acc[i][j] = (f32x4)0.0f;

#define STAGE(buf, ks) do {                                             \
        unsigned char* _b = lds + (buf) * 32768;                        \
        async16(gA0 + (ks) * 32, _b +         (2*w    ) * 1024);        \
        async16(gA1 + (ks) * 32, _b +         (2*w + 1) * 1024);        \
        async16(gB0 + (ks) * 32, _b + 16384 + (2*w    ) * 1024);        \
        async16(gB1 + (ks) * 32, _b + 16384 + (2*w + 1) * 1024);        \
    } while (0)

        STAGE(0, 0);
        STAGE(1, 1);
        asm volatile("s_waitcnt vmcnt(4)" ::: "memory");   // stage(0) landed
        __builtin_amdgcn_s_barrier();
        asm volatile("" ::: "memory");

        #pragma unroll
        for (int ks = 0; ks < 8; ++ks) {
            if (ks < 6) STAGE((ks + 2) % 3, ks + 2);       // 2 tiles ahead

            const unsigned char* ba = lds + (ks % 3) * 32768;
            bf16x8 af[8], bf[4];
            #pragma unroll
            for (int i = 0; i < 8; ++i)
                af[i] = *(const bf16x8*)(ba + (wr*8 + i) * 1024 + quad * 256 + l16 * 16);
            #pragma unroll
            for (int j = 0; j < 4; ++j)
                bf[j] = *(const bf16x8*)(ba + 16384 + (wc*4 + j) * 1024 + quad * 256 + l16 * 16);

            #pragma unroll
            for (int i = 0; i < 8; ++i)
                #pragma unroll
                for (int j = 0; j < 4; ++j)
                    acc[i][j] = __builtin_amdgcn_mfma_f32_16x16x32_bf16(
                        af[i], bf[j], acc[i][j], 0, 0, 0);

            if (ks < 7) {
                if (ks < 6) { asm volatile("s_waitcnt vmcnt(4)" ::: "memory"); }
                else        { asm volatile("s_waitcnt vmcnt(0)" ::: "memory"); }
                __builtin_amdgcn_s_barrier();
                asm volatile("" ::: "memory");
            }
        }
#undef STAGE

        // tile epilogue: exp + partial rowsums into part[colblk]
        __syncthreads();                   // staged tiles consumed; reuse LDS
        float* red = (float*)lds;          // 4 x 256 floats: [wc][256 rows]

        #pragma unroll
        for (int i = 0; i < 8; ++i)
            #pragma unroll
            for (int r = 0; r < 4; ++r) {
                float s = __expf(acc[i][0][r] * INV_TEMP)
                        + __expf(acc[i][1][r] * INV_TEMP)
                        + __expf(acc[i][2][r] * INV_TEMP)
                        + __expf(acc[i][3][r] * INV_TEMP);
                s += __shfl_xor(s, 1);
                s += __shfl_xor(s, 2);
                s += __shfl_xor(s, 4);
                s += __shfl_xor(s, 8);
                if (l16 == 0)
                    red[wc * 256 + wr * 128 + i * 16 + quad * 4 + r] = s;
            }
        __syncthreads();

        if (tid < 256)
            part[(size_t)colblk * NROWS + rowbase + tid] =
                red[tid] + red[256 + tid] + red[512 + tid] + red[768 + tid];
        __syncthreads();                   // red[] reads done before next tile
    }

    __threadfence();
    grid.sync();
    __threadfence();

    // ================= Phase 3: rowsum for rows [b*32, b*32+32) ===========
    {
        const int r32 = tid & 31;          // row within block slice
        const int sl  = tid >> 5;          // 0..15: colblock slice (2 each)
        const int row = b * 32 + r32;
        float s = part[(size_t)(2*sl    ) * NROWS + row]
                + part[(size_t)(2*sl + 1) * NROWS + row];
        float* psum = (float*)lds;         // [32][17] padded
        psum[r32 * 17 + sl] = s;
        __syncthreads();

        if (tid < 32) {
            float tot = 0.0f;
            #pragma unroll
            for (int s16 = 0; s16 < 16; ++s16) tot += psum[tid * 17 + s16];
            float v = logf(tot) - diag[b * 32 + tid];
            #pragma unroll
            for (int m = 1; m < 32; m <<= 1) v += __shfl_xor(v, m);
            if (tid == 0) loss_part[b] = v;
        }
    }

    __threadfence();
    grid.sync();
    __threadfence();

    // ================= Phase 4: block 0 reduces 256 partials ==============
    if (b == 0) {
        float v = (tid < 256) ? loss_part[tid] : 0.0f;
        #pragma unroll
        for (int m = 1; m < 64; m <<= 1) v += __shfl_xor(v, m);
        float* ws8 = (float*)lds;
        if (lane == 0) ws8[w] = v;
        __syncthreads();
        if (tid == 0)
            out[0] = (ws8[0] + ws8[1] + ws8[2] + ws8[3] +
                      ws8[4] + ws8[5] + ws8[6] + ws8[7]) * (1.0f / NROWS);
    }
}

// ---------------------------------------------------------------------------
extern "C" void kernel_launch(void* const* d_in, const int* in_sizes, int n_in,
                              void* d_out, int out_size, void* d_ws, size_t ws_size,
                              hipStream_t stream)
{
    const float* q = (const float*)d_in[0];
    const float* p = (const float*)d_in[1];

    char* ws = (char*)d_ws;
    unsigned short* qn   = (unsigned short*)ws;                          // 4 MB
    unsigned short* pn   = (unsigned short*)(ws + (size_t)NROWS*DDIM*2); // 4 MB
    float* part      = (float*)(ws + 2*(size_t)NROWS*DDIM*2);            // 1 MB
    float* diag      = part + 32 * (size_t)NROWS;                        // 32 KB
    float* loss_part = diag + NROWS;                                     // 1 KB
    float* outp      = (float*)d_out;

    void* args[] = { (void*)&q, (void*)&p, (void*)&qn, (void*)&pn,
                     (void*)&diag, (void*)&part, (void*)&loss_part,
                     (void*)&outp };

    hipLaunchCooperativeKernel((const void*)simcse_fused_kernel,
                               dim3(256), dim3(512), args, 0, stream);
}

// Round 9
// 266.047 us; speedup vs baseline: 1.5827x; 1.5827x over previous
//
#include <hip/hip_runtime.h>
#include <hip/hip_bf16.h>

#define NROWS 8192
#define DDIM  256
#define INV_TEMP 20.0f   // 1/0.05

typedef __attribute__((ext_vector_type(8))) short bf16x8;
typedef __attribute__((ext_vector_type(4))) float f32x4;

// async global->LDS, 16B per lane. LDS dest = uniform base + lane*16.
__device__ static inline void async16(const void* g, void* l) {
    __builtin_amdgcn_global_load_lds(
        (const __attribute__((address_space(1))) void*)g,
        (__attribute__((address_space(3))) void*)l, 16, 0, 0);
}

// ---------------------------------------------------------------------------
// Kernel 1: per-row L2-normalize q and p (fp32), emit bf16 copies (linear
// row-major), fp32 diag. One wave per row, 4 rows per block. Block 0 zeroes
// the 33 cacheline-padded tickets (stream-ordered before kernel 2; re-zeroed
// every invocation so graph replay is safe).
// ---------------------------------------------------------------------------
__global__ __launch_bounds__(256) void norm_diag_kernel(
    const float* __restrict__ q, const float* __restrict__ p,
    unsigned short* __restrict__ qn, unsigned short* __restrict__ pn,
    float* __restrict__ diag, int* __restrict__ tickets)
{
    if (blockIdx.x == 0 && threadIdx.x < 33)
        tickets[threadIdx.x * 32] = 0;   // [rb*32] rb=0..31, done at [32*32]

    const int row  = (blockIdx.x << 2) + (threadIdx.x >> 6);
    const int lane = threadIdx.x & 63;

    const float4 qv = ((const float4*)(q + (size_t)row * DDIM))[lane];
    const float4 pv = ((const float4*)(p + (size_t)row * DDIM))[lane];

    float sq = qv.x*qv.x + qv.y*qv.y + qv.z*qv.z + qv.w*qv.w;
    float sp = pv.x*pv.x + pv.y*pv.y + pv.z*pv.z + pv.w*pv.w;
    #pragma unroll
    for (int m = 1; m < 64; m <<= 1) {
        sq += __shfl_xor(sq, m);
        sp += __shfl_xor(sp, m);
    }
    const float qs = 1.0f / fmaxf(sqrtf(sq), 1e-8f);
    const float ps = 1.0f / fmaxf(sqrtf(sp), 1e-8f);

    const float qx = qv.x*qs, qy = qv.y*qs, qz = qv.z*qs, qw = qv.w*qs;
    const float px = pv.x*ps, py = pv.y*ps, pz = pv.z*ps, pw = pv.w*ps;

    float d = qx*px + qy*py + qz*pz + qw*pw;
    #pragma unroll
    for (int m = 1; m < 64; m <<= 1) d += __shfl_xor(d, m);
    if (lane == 0) diag[row] = d * INV_TEMP;

    union { unsigned short u16[4]; uint2 v; } uq, up;
    {
        __hip_bfloat16 b;
        b = __float2bfloat16(qx); uq.u16[0] = *(unsigned short*)&b;
        b = __float2bfloat16(qy); uq.u16[1] = *(unsigned short*)&b;
        b = __float2bfloat16(qz); uq.u16[2] = *(unsigned short*)&b;
        b = __float2bfloat16(qw); uq.u16[3] = *(unsigned short*)&b;
        b = __float2bfloat16(px); up.u16[0] = *(unsigned short*)&b;
        b = __float2bfloat16(py); up.u16[1] = *(unsigned short*)&b;
        b = __float2bfloat16(pz); up.u16[2] = *(unsigned short*)&b;
        b = __float2bfloat16(pw); up.u16[3] = *(unsigned short*)&b;
    }
    *(uint2*)(qn + (size_t)row * DDIM + lane * 4) = uq.v;
    *(uint2*)(pn + (size_t)row * DDIM + lane * 4) = up.v;
}

// ---------------------------------------------------------------------------
// Kernel 2: fused GEMM + sum-exp (R6 core, byte-identical) + fused rowsum /
// final via SPREAD completion tickets.
// 256x256 tile, 512 threads = 8 waves (2x4), wave tile 128x64, BK=32 x 8,
// 3 LDS buffers, depth-2 prefetch, counted vmcnt(4) (never 0 in-loop).
//
// Ticket scale math (R4 lesson): 32 row-tickets, EACH on its own 128B
// cacheline -> 32 arrivals per ticket, parallel across tickets (~2-3 us
// total), not R4's 4096 serialized RMWs on 2 cachelines (~330 us). The
// 32nd arrival per rowblock becomes the finisher for its 256 rows
// (summation order identical to the old rowsum_final_kernel); the 32nd
// finisher reduces the 32 loss partials. No spinning -> dispatch-order safe.
// ---------------------------------------------------------------------------
__global__ __launch_bounds__(512, 2) void simexp_kernel(
    const unsigned short* __restrict__ qn,
    const unsigned short* __restrict__ pn,
    float* __restrict__ part,        // [32 colblocks][8192 rows]
    const float* __restrict__ diag,
    float* __restrict__ loss_part,   // [32]
    int* __restrict__ tickets,       // [33*32], stride-32 (128B) per ticket
    float* __restrict__ out)
{
    __shared__ unsigned char lds[3 * 32768];   // 3 x (As 16KB | Bs 16KB)

    const int tid  = threadIdx.x;
    const int lane = tid & 63;
    const int w    = tid >> 6;        // wave 0..7
    const int wr   = w >> 2;          // wave row (0..1): 128 rows each
    const int wc   = w & 3;           // wave col (0..3): 64 cols each
    const int quad = lane >> 4;
    const int l16  = lane & 15;

    // ---- XCD-chunked swizzle (bijective on 1024 blocks) ----
    const int L   = blockIdx.y * 32 + blockIdx.x;
    const int xcd = L & 7;
    const int c   = L >> 3;
    const int rowblk = xcd * 4 + (c & 3);
    const int colblk = c >> 2;
    const int rowbase = rowblk * 256;
    const int colbase = colblk * 256;

    const unsigned short* gA0 = qn + (size_t)(rowbase + (2*w  )*16 + l16) * DDIM + quad * 8;
    const unsigned short* gA1 = qn + (size_t)(rowbase + (2*w+1)*16 + l16) * DDIM + quad * 8;
    const unsigned short* gB0 = pn + (size_t)(colbase + (2*w  )*16 + l16) * DDIM + quad * 8;
    const unsigned short* gB1 = pn + (size_t)(colbase + (2*w+1)*16 + l16) * DDIM + quad * 8;

    f32x4 acc[8][4];
    #pragma unroll
    for (int i = 0; i < 8; ++i)
        #pragma unroll
        for (int j = 0; j < 4; ++j) acc[i][j] = (f32x4)0.0f;

#define STAGE(buf, ks) do {                                             \
        unsigned char* _b = lds + (buf) * 32768;                        \
        async16(gA0 + (ks) * 32, _b +         (2*w    ) * 1024);        \
        async16(gA1 + (ks) * 32, _b +         (2*w + 1) * 1024);        \
        async16(gB0 + (ks) * 32, _b + 16384 + (2*w    ) * 1024);        \
        async16(gB1 + (ks) * 32, _b + 16384 + (2*w + 1) * 1024);        \
    } while (0)

    STAGE(0, 0);
    STAGE(1, 1);
    asm volatile("s_waitcnt vmcnt(4)" ::: "memory");   // stage(0) landed
    __builtin_amdgcn_s_barrier();
    asm volatile("" ::: "memory");

    #pragma unroll
    for (int ks = 0; ks < 8; ++ks) {
        if (ks < 6) STAGE((ks + 2) % 3, ks + 2);       // issue 2 tiles ahead

        const unsigned char* ba = lds + (ks % 3) * 32768;
        bf16x8 af[8], bf[4];
        #pragma unroll
        for (int i = 0; i < 8; ++i)
            af[i] = *(const bf16x8*)(ba + (wr*8 + i) * 1024 + quad * 256 + l16 * 16);
        #pragma unroll
        for (int j = 0; j < 4; ++j)
            bf[j] = *(const bf16x8*)(ba + 16384 + (wc*4 + j) * 1024 + quad * 256 + l16 * 16);

        #pragma unroll
        for (int i = 0; i < 8; ++i)
            #pragma unroll
            for (int j = 0; j < 4; ++j)
                acc[i][j] = __builtin_amdgcn_mfma_f32_16x16x32_bf16(
                    af[i], bf[j], acc[i][j], 0, 0, 0);

        if (ks < 7) {
            if (ks < 6) { asm volatile("s_waitcnt vmcnt(4)" ::: "memory"); }
            else        { asm volatile("s_waitcnt vmcnt(0)" ::: "memory"); }
            __builtin_amdgcn_s_barrier();
            asm volatile("" ::: "memory");
        }
    }
#undef STAGE

    // epilogue: exp + partial rowsums -------------------------------------
    __syncthreads();                   // all ds_reads done; reuse LDS
    float* red = (float*)lds;          // 4 x 256 floats: [wc][256 rows]

    #pragma unroll
    for (int i = 0; i < 8; ++i)
        #pragma unroll
        for (int r = 0; r < 4; ++r) {
            float s = __expf(acc[i][0][r] * INV_TEMP)
                    + __expf(acc[i][1][r] * INV_TEMP)
                    + __expf(acc[i][2][r] * INV_TEMP)
                    + __expf(acc[i][3][r] * INV_TEMP);
            s += __shfl_xor(s, 1);
            s += __shfl_xor(s, 2);
            s += __shfl_xor(s, 4);
            s += __shfl_xor(s, 8);
            if (l16 == 0)
                red[wc * 256 + wr * 128 + i * 16 + quad * 4 + r] = s;
        }
    __syncthreads();

    if (tid < 256)
        part[(size_t)colblk * NROWS + rowbase + tid] =
            red[tid] + red[256 + tid] + red[512 + tid] + red[768 + tid];

    // ---- fused rowsum via spread completion tickets ----------------------
    __threadfence();                   // push part[] writes out (agent)
    __syncthreads();
    __shared__ int swin;
    __shared__ int sdone;
    if (tid == 0)
        swin = __hip_atomic_fetch_add(&tickets[rowblk * 32], 1,
                   __ATOMIC_ACQ_REL, __HIP_MEMORY_SCOPE_AGENT);
    __syncthreads();
    if (swin != 31) return;            // not the last colblock for this row

    // winner: per-row totals for rows [rowbase, rowbase+256) --------------
    float* wsum = (float*)lds;         // 8 floats (one per wave)
    float v = 0.0f;
    if (tid < 256) {
        const int row = rowbase + tid;
        float s = 0.0f;
        #pragma unroll 4
        for (int cb = 0; cb < 32; ++cb)
            s += __hip_atomic_load(&part[(size_t)cb * NROWS + row],
                     __ATOMIC_RELAXED, __HIP_MEMORY_SCOPE_AGENT);
        v = logf(s) - diag[row];
    }
    #pragma unroll
    for (int m = 1; m < 64; m <<= 1) v += __shfl_xor(v, m);
    if (lane == 0) wsum[w] = v;        // waves 4..7 contribute 0
    __syncthreads();
    if (tid == 0) {
        __hip_atomic_store(&loss_part[rowblk],
            wsum[0] + wsum[1] + wsum[2] + wsum[3] +
            wsum[4] + wsum[5] + wsum[6] + wsum[7],
            __ATOMIC_RELEASE, __HIP_MEMORY_SCOPE_AGENT);
        const int d = __hip_atomic_fetch_add(&tickets[32 * 32], 1,
                          __ATOMIC_ACQ_REL, __HIP_MEMORY_SCOPE_AGENT);
        sdone = (d == 31);
    }
    __syncthreads();
    if (!sdone) return;

    // last finisher: final mean over 32 rowblock partials -----------------
    if (tid < 32) {
        float x = __hip_atomic_load(&loss_part[tid],
                      __ATOMIC_RELAXED, __HIP_MEMORY_SCOPE_AGENT);
        #pragma unroll
        for (int m = 1; m < 32; m <<= 1) x += __shfl_xor(x, m);
        if (tid == 0) out[0] = x * (1.0f / NROWS);
    }
}

// ---------------------------------------------------------------------------
extern "C" void kernel_launch(void* const* d_in, const int* in_sizes, int n_in,
                              void* d_out, int out_size, void* d_ws, size_t ws_size,
                              hipStream_t stream)
{
    const float* q = (const float*)d_in[0];
    const float* p = (const float*)d_in[1];

    char* ws = (char*)d_ws;
    unsigned short* qn   = (unsigned short*)ws;                          // 4 MB
    unsigned short* pn   = (unsigned short*)(ws + (size_t)NROWS*DDIM*2); // 4 MB
    float* part      = (float*)(ws + 2*(size_t)NROWS*DDIM*2);            // 1 MB
    float* diag      = part + 32 * (size_t)NROWS;                        // 32 KB
    float* loss_part = diag + NROWS;                                     // 128 B
    int*   tickets   = (int*)(loss_part + 32);                           // 33*128B

    norm_diag_kernel<<<NROWS/4, 256, 0, stream>>>(q, p, qn, pn, diag, tickets);

    dim3 grid(32, 32);   // colblocks x rowblocks (remapped in-kernel)
    simexp_kernel<<<grid, 512, 0, stream>>>(qn, pn, part, diag, loss_part,
                                            tickets, (float*)d_out);
}

// Round 10
// 160.900 us; speedup vs baseline: 2.6170x; 1.6535x over previous
//
#include <hip/hip_runtime.h>
#include <hip/hip_bf16.h>

#define NROWS 8192
#define DDIM  256
#define INV_TEMP 20.0f   // 1/0.05

typedef __attribute__((ext_vector_type(8))) short bf16x8;
typedef __attribute__((ext_vector_type(16))) float f32x16;

// async global->LDS, 16B per lane. LDS dest = uniform base + lane*16.
__device__ static inline void async16(const void* g, void* l) {
    __builtin_amdgcn_global_load_lds(
        (const __attribute__((address_space(1))) void*)g,
        (__attribute__((address_space(3))) void*)l, 16, 0, 0);
}

// ---------------------------------------------------------------------------
// Kernel 1: per-row L2-normalize q and p (fp32), emit bf16 copies (linear
// row-major), fp32 diag. One wave per row, 4 rows per block. Block 0 zeroes
// the rowsum ticket (stream-ordered before kernel 3; graph-replay safe).
// ---------------------------------------------------------------------------
__global__ __launch_bounds__(256) void norm_diag_kernel(
    const float* __restrict__ q, const float* __restrict__ p,
    unsigned short* __restrict__ qn, unsigned short* __restrict__ pn,
    float* __restrict__ diag, int* __restrict__ tickets)
{
    if (blockIdx.x == 0 && threadIdx.x == 0) tickets[0] = 0;

    const int row  = (blockIdx.x << 2) + (threadIdx.x >> 6);
    const int lane = threadIdx.x & 63;

    const float4 qv = ((const float4*)(q + (size_t)row * DDIM))[lane];
    const float4 pv = ((const float4*)(p + (size_t)row * DDIM))[lane];

    float sq = qv.x*qv.x + qv.y*qv.y + qv.z*qv.z + qv.w*qv.w;
    float sp = pv.x*pv.x + pv.y*pv.y + pv.z*pv.z + pv.w*pv.w;
    #pragma unroll
    for (int m = 1; m < 64; m <<= 1) {
        sq += __shfl_xor(sq, m);
        sp += __shfl_xor(sp, m);
    }
    const float qs = 1.0f / fmaxf(sqrtf(sq), 1e-8f);
    const float ps = 1.0f / fmaxf(sqrtf(sp), 1e-8f);

    const float qx = qv.x*qs, qy = qv.y*qs, qz = qv.z*qs, qw = qv.w*qs;
    const float px = pv.x*ps, py = pv.y*ps, pz = pv.z*ps, pw = pv.w*ps;

    float d = qx*px + qy*py + qz*pz + qw*pw;
    #pragma unroll
    for (int m = 1; m < 64; m <<= 1) d += __shfl_xor(d, m);
    if (lane == 0) diag[row] = d * INV_TEMP;

    union { unsigned short u16[4]; uint2 v; } uq, up;
    {
        __hip_bfloat16 b;
        b = __float2bfloat16(qx); uq.u16[0] = *(unsigned short*)&b;
        b = __float2bfloat16(qy); uq.u16[1] = *(unsigned short*)&b;
        b = __float2bfloat16(qz); uq.u16[2] = *(unsigned short*)&b;
        b = __float2bfloat16(qw); uq.u16[3] = *(unsigned short*)&b;
        b = __float2bfloat16(px); up.u16[0] = *(unsigned short*)&b;
        b = __float2bfloat16(py); up.u16[1] = *(unsigned short*)&b;
        b = __float2bfloat16(pz); up.u16[2] = *(unsigned short*)&b;
        b = __float2bfloat16(pw); up.u16[3] = *(unsigned short*)&b;
    }
    *(uint2*)(qn + (size_t)row * DDIM + lane * 4) = uq.v;
    *(uint2*)(pn + (size_t)row * DDIM + lane * 4) = up.v;
}

// ---------------------------------------------------------------------------
// Kernel 2: fused GEMM + sum-exp, R6 shell (256x256 tile, 8 waves 2x4,
// BK=32 x 8, 3 LDS buffers, depth-2 prefetch, counted vmcnt(4)) with the
// MFMA shape switched 16x16x32 -> 32x32x16:
//   - 16 MFMA per wave per K-step instead of 32 (half the issue slots)
//   - matrix-pipe rate 2382 vs 2075 TF (u-bench)
//   - SAME 12 ds_read_b128 per wave per K-step, SAME staging bytes
// Wave tile 128x64 = 4 row-subtiles x 2 col-subtiles of 32; acc f32x16[4][2].
// A-frag (lane l): row l&31, k (l>>5)*8..+8 -> LDS addr
//   subtile_base + ((l&31)>>4)*1024 + (s*2 + (l>>5))*256 + (l&15)*16
// (dense 16B coverage of two 512B regions -> conflict-free).
// C/D layout (m74/m101): col=lane&31, row=(reg&3)+8*(reg>>2)+4*(lane>>5).
// ---------------------------------------------------------------------------
__global__ __launch_bounds__(512, 2) void simexp_kernel(
    const unsigned short* __restrict__ qn,
    const unsigned short* __restrict__ pn,
    float* __restrict__ part)       // [32 colblocks][8192 rows]
{
    __shared__ unsigned char lds[3 * 32768];   // 3 x (As 16KB | Bs 16KB)

    const int tid  = threadIdx.x;
    const int lane = tid & 63;
    const int w    = tid >> 6;        // wave 0..7
    const int wr   = w >> 2;          // wave row (0..1): 128 rows each
    const int wc   = w & 3;           // wave col (0..3): 64 cols each
    const int l16  = lane & 15;
    const int quad = lane >> 4;

    // per-lane fragment offset within a 2-tile (2KB) subtile, before s*512
    const int a_off = ((lane & 31) >> 4) * 1024 + (lane >> 5) * 256 + l16 * 16;

    // ---- XCD-chunked swizzle (bijective on 1024 blocks) ----
    const int L   = blockIdx.y * 32 + blockIdx.x;
    const int xcd = L & 7;
    const int c   = L >> 3;
    const int rowblk = xcd * 4 + (c & 3);
    const int colblk = c >> 2;
    const int rowbase = rowblk * 256;
    const int colbase = colblk * 256;

    // staging sources (unchanged from R6): wave w stages 16-row tiles
    // {2w, 2w+1} of A and B. lane l -> row (l&15), 16B chunk (l>>4).
    const unsigned short* gA0 = qn + (size_t)(rowbase + (2*w  )*16 + l16) * DDIM + quad * 8;
    const unsigned short* gA1 = qn + (size_t)(rowbase + (2*w+1)*16 + l16) * DDIM + quad * 8;
    const unsigned short* gB0 = pn + (size_t)(colbase + (2*w  )*16 + l16) * DDIM + quad * 8;
    const unsigned short* gB1 = pn + (size_t)(colbase + (2*w+1)*16 + l16) * DDIM + quad * 8;

    f32x16 acc[4][2];
    #pragma unroll
    for (int i = 0; i < 4; ++i)
        #pragma unroll
        for (int j = 0; j < 2; ++j) acc[i][j] = (f32x16)0.0f;

#define STAGE(buf, ks) do {                                             \
        unsigned char* _b = lds + (buf) * 32768;                        \
        async16(gA0 + (ks) * 32, _b +         (2*w    ) * 1024);        \
        async16(gA1 + (ks) * 32, _b +         (2*w + 1) * 1024);        \
        async16(gB0 + (ks) * 32, _b + 16384 + (2*w    ) * 1024);        \
        async16(gB1 + (ks) * 32, _b + 16384 + (2*w + 1) * 1024);        \
    } while (0)

    STAGE(0, 0);
    STAGE(1, 1);
    asm volatile("s_waitcnt vmcnt(4)" ::: "memory");   // stage(0) landed
    __builtin_amdgcn_s_barrier();
    asm volatile("" ::: "memory");

    #pragma unroll
    for (int ks = 0; ks < 8; ++ks) {
        if (ks < 6) STAGE((ks + 2) % 3, ks + 2);       // issue 2 tiles ahead

        const unsigned char* ba = lds + (ks % 3) * 32768;
        bf16x8 af[2][4], bf[2][2];
        #pragma unroll
        for (int s = 0; s < 2; ++s) {
            #pragma unroll
            for (int i = 0; i < 4; ++i)
                af[s][i] = *(const bf16x8*)(ba + (wr*8 + i*2) * 1024 + a_off + s * 512);
            #pragma unroll
            for (int j = 0; j < 2; ++j)
                bf[s][j] = *(const bf16x8*)(ba + 16384 + (wc*4 + j*2) * 1024 + a_off + s * 512);
        }

        #pragma unroll
        for (int s = 0; s < 2; ++s)
            #pragma unroll
            for (int i = 0; i < 4; ++i)
                #pragma unroll
                for (int j = 0; j < 2; ++j)
                    acc[i][j] = __builtin_amdgcn_mfma_f32_32x32x16_bf16(
                        af[s][i], bf[s][j], acc[i][j], 0, 0, 0);

        if (ks < 7) {
            if (ks < 6) { asm volatile("s_waitcnt vmcnt(4)" ::: "memory"); }
            else        { asm volatile("s_waitcnt vmcnt(0)" ::: "memory"); }
            __builtin_amdgcn_s_barrier();
            asm volatile("" ::: "memory");
        }
    }
#undef STAGE

    // epilogue ------------------------------------------------------------
    __syncthreads();                   // all ds_reads done; reuse LDS
    float* red = (float*)lds;          // 4 x 256 floats: [wc][256 rows]

    // C/D: col = lane&31 (within 32-col subtile j), row = (reg&3)+8*(reg>>2)
    // +4*(lane>>5) (within 32-row subtile i). Sum exp over j then over the
    // 32 cols via 5-step shuffle tree (xor<=16 stays within each 32-group).
    #pragma unroll
    for (int i = 0; i < 4; ++i)
        #pragma unroll
        for (int reg = 0; reg < 16; ++reg) {
            float s = __expf(acc[i][0][reg] * INV_TEMP)
                    + __expf(acc[i][1][reg] * INV_TEMP);
            s += __shfl_xor(s, 1);
            s += __shfl_xor(s, 2);
            s += __shfl_xor(s, 4);
            s += __shfl_xor(s, 8);
            s += __shfl_xor(s, 16);
            if ((lane & 31) == 0)
                red[wc * 256 + wr * 128 + i * 32
                    + (reg & 3) + 8 * (reg >> 2) + ((lane >> 5) << 2)] = s;
        }
    __syncthreads();

    if (tid < 256)
        part[(size_t)colblk * NROWS + rowbase + tid] =
            red[tid] + red[256 + tid] + red[512 + tid] + red[768 + tid];
}

// ---------------------------------------------------------------------------
// Kernel 3: per-row total + log - diag, block partials, fused final mean via
// a 64-block completion ticket (64 agent-scope RMWs, us-scale — R6-proven).
// ---------------------------------------------------------------------------
__global__ __launch_bounds__(128) void rowsum_final_kernel(
    const float* __restrict__ part, const float* __restrict__ diag,
    float* __restrict__ loss_part, int* __restrict__ tickets,
    float* __restrict__ out)
{
    const int row = blockIdx.x * 128 + threadIdx.x;
    float s = 0.0f;
    #pragma unroll 4
    for (int cb = 0; cb < 32; ++cb)
        s += part[(size_t)cb * NROWS + row];     // coalesced across threads
    float v = logf(s) - diag[row];

    #pragma unroll
    for (int m = 1; m < 64; m <<= 1) v += __shfl_xor(v, m);
    __shared__ float wsum[2];
    __shared__ int swin;
    if ((threadIdx.x & 63) == 0) wsum[threadIdx.x >> 6] = v;
    __syncthreads();
    if (threadIdx.x == 0) {
        __hip_atomic_store(&loss_part[blockIdx.x], wsum[0] + wsum[1],
            __ATOMIC_RELEASE, __HIP_MEMORY_SCOPE_AGENT);
        swin = __hip_atomic_fetch_add(&tickets[0], 1,
                   __ATOMIC_ACQ_REL, __HIP_MEMORY_SCOPE_AGENT);
    }
    __syncthreads();
    if (swin != 63) return;            // not the last block

    if (threadIdx.x < 64) {
        float x = __hip_atomic_load(&loss_part[threadIdx.x],
                      __ATOMIC_RELAXED, __HIP_MEMORY_SCOPE_AGENT);
        #pragma unroll
        for (int m = 1; m < 64; m <<= 1) x += __shfl_xor(x, m);
        if (threadIdx.x == 0) out[0] = x * (1.0f / NROWS);
    }
}

// ---------------------------------------------------------------------------
extern "C" void kernel_launch(void* const* d_in, const int* in_sizes, int n_in,
                              void* d_out, int out_size, void* d_ws, size_t ws_size,
                              hipStream_t stream)
{
    const float* q = (const float*)d_in[0];
    const float* p = (const float*)d_in[1];

    char* ws = (char*)d_ws;
    unsigned short* qn   = (unsigned short*)ws;                          // 4 MB
    unsigned short* pn   = (unsigned short*)(ws + (size_t)NROWS*DDIM*2); // 4 MB
    float* part      = (float*)(ws + 2*(size_t)NROWS*DDIM*2);            // 1 MB
    float* diag      = part + 32 * (size_t)NROWS;                        // 32 KB
    float* loss_part = diag + NROWS;                                     // 256 B
    int*   tickets   = (int*)(loss_part + 64);

    norm_diag_kernel<<<NROWS/4, 256, 0, stream>>>(q, p, qn, pn, diag, tickets);

    dim3 grid(32, 32);   // colblocks x rowblocks (remapped in-kernel)
    simexp_kernel<<<grid, 512, 0, stream>>>(qn, pn, part);

    rowsum_final_kernel<<<64, 128, 0, stream>>>(part, diag, loss_part,
                                                tickets, (float*)d_out);
}

// Round 11
// 125.007 us; speedup vs baseline: 3.3684x; 1.2871x over previous
//
#include <hip/hip_runtime.h>
#include <hip/hip_bf16.h>

#define NROWS 8192
#define DDIM  256
#define INV_TEMP 20.0f   // 1/0.05

typedef __attribute__((ext_vector_type(8))) short bf16x8;
typedef __attribute__((ext_vector_type(4))) float f32x4;

// async global->LDS, 16B per lane. LDS dest = uniform base (+ lane*16 by HW).
__device__ static inline void async16(const void* g, void* l) {
    __builtin_amdgcn_global_load_lds(
        (const __attribute__((address_space(1))) void*)g,
        (__attribute__((address_space(3))) void*)l, 16, 0, 0);
}

// ---------------------------------------------------------------------------
// Kernel 1: per-row L2-normalize q and p (fp32), emit bf16 copies (linear
// row-major), fp32 diag. One wave per row, 4 rows per block. Block 0 zeroes
// the rowsum ticket (stream-ordered before kernel 3; graph-replay safe).
// ---------------------------------------------------------------------------
__global__ __launch_bounds__(256) void norm_diag_kernel(
    const float* __restrict__ q, const float* __restrict__ p,
    unsigned short* __restrict__ qn, unsigned short* __restrict__ pn,
    float* __restrict__ diag, int* __restrict__ tickets)
{
    if (blockIdx.x == 0 && threadIdx.x == 0) tickets[0] = 0;

    const int row  = (blockIdx.x << 2) + (threadIdx.x >> 6);
    const int lane = threadIdx.x & 63;

    const float4 qv = ((const float4*)(q + (size_t)row * DDIM))[lane];
    const float4 pv = ((const float4*)(p + (size_t)row * DDIM))[lane];

    float sq = qv.x*qv.x + qv.y*qv.y + qv.z*qv.z + qv.w*qv.w;
    float sp = pv.x*pv.x + pv.y*pv.y + pv.z*pv.z + pv.w*pv.w;
    #pragma unroll
    for (int m = 1; m < 64; m <<= 1) {
        sq += __shfl_xor(sq, m);
        sp += __shfl_xor(sp, m);
    }
    const float qs = 1.0f / fmaxf(sqrtf(sq), 1e-8f);
    const float ps = 1.0f / fmaxf(sqrtf(sp), 1e-8f);

    const float qx = qv.x*qs, qy = qv.y*qs, qz = qv.z*qs, qw = qv.w*qs;
    const float px = pv.x*ps, py = pv.y*ps, pz = pv.z*ps, pw = pv.w*ps;

    float d = qx*px + qy*py + qz*pz + qw*pw;
    #pragma unroll
    for (int m = 1; m < 64; m <<= 1) d += __shfl_xor(d, m);
    if (lane == 0) diag[row] = d * INV_TEMP;

    union { unsigned short u16[4]; uint2 v; } uq, up;
    {
        __hip_bfloat16 b;
        b = __float2bfloat16(qx); uq.u16[0] = *(unsigned short*)&b;
        b = __float2bfloat16(qy); uq.u16[1] = *(unsigned short*)&b;
        b = __float2bfloat16(qz); uq.u16[2] = *(unsigned short*)&b;
        b = __float2bfloat16(qw); uq.u16[3] = *(unsigned short*)&b;
        b = __float2bfloat16(px); up.u16[0] = *(unsigned short*)&b;
        b = __float2bfloat16(py); up.u16[1] = *(unsigned short*)&b;
        b = __float2bfloat16(pz); up.u16[2] = *(unsigned short*)&b;
        b = __float2bfloat16(pw); up.u16[3] = *(unsigned short*)&b;
    }
    *(uint2*)(qn + (size_t)row * DDIM + lane * 4) = uq.v;
    *(uint2*)(pn + (size_t)row * DDIM + lane * 4) = up.v;
}

// ---------------------------------------------------------------------------
// Kernel 2: fused GEMM + sum-exp, 256x128 tile, 2 BLOCKS/CU.
// The untested {tile, blocks/CU} cell: R1 = 128²@3/CU (69.8us), R6 = 256²@1/CU
// (65.0us, zero inter-block TLP). This: per-buffer LDS = A 16K + B 8K = 24KB,
// 3 buffers = 72KB -> 2 blocks/CU, 16 waves/CU, full depth-2 counted-vmcnt
// pipeline retained. When one block sits at vmcnt/barrier, the co-resident
// block's waves issue MFMA (m114 co-scheduling) — isolates inter-block TLP
// as latency cover for the lockstep pipeline.
// 8 waves (4 row x 2 col), wave tile 64x64: af[4]/bf[4]/acc[4][4], 16
// MFMA/K-step (R1's proven 68-VGPR per-wave shape). Staging: 24 tiles
// (16 A + 8 B) over 8 waves = 3 per wave -> vmcnt granularity 3.
// ---------------------------------------------------------------------------
__global__ __launch_bounds__(512, 4) void simexp_kernel(
    const unsigned short* __restrict__ qn,
    const unsigned short* __restrict__ pn,
    float* __restrict__ part)       // [64 colblocks][8192 rows]
{
    __shared__ unsigned char lds[3 * 24576];   // 3 x (As 16KB | Bs 8KB)

    const int tid  = threadIdx.x;
    const int lane = tid & 63;
    const int w    = tid >> 6;        // wave 0..7
    const int wr   = w >> 1;          // wave row (0..3): 64 rows each
    const int wc   = w & 1;           // wave col (0..1): 64 cols each
    const int quad = lane >> 4;
    const int l16  = lane & 15;
    const int loff = lane * 16;       // = quad*256 + l16*16

    // ---- XCD-chunked swizzle (bijective on 2048 blocks) ----
    const int L   = blockIdx.x;
    const int xcd = L & 7;
    const int c   = L >> 3;                    // 0..255
    const int rowblk = xcd * 4 + (c & 3);      // 32 rowblocks of 256 rows
    const int colblk = c >> 2;                 // 64 colblocks of 128 cols
    const int rowbase = rowblk * 256;
    const int colbase = colblk * 128;

    // staging: 24 16-row tiles per K-step (A: 0..15, B: 16..23); wave w owns
    // tiles {3w, 3w+1, 3w+2}. lane l -> row (l&15), 16B chunk (l>>4).
    const unsigned short* gsrc0; const unsigned short* gsrc1;
    const unsigned short* gsrc2;
    int ldst0, ldst1, ldst2;
    {
        const int i0 = 3*w, i1 = 3*w + 1, i2 = 3*w + 2;
        gsrc0 = (i0 < 16) ? qn + (size_t)(rowbase + i0*16 + l16) * DDIM + quad * 8
                          : pn + (size_t)(colbase + (i0-16)*16 + l16) * DDIM + quad * 8;
        ldst0 = (i0 < 16) ? i0 * 1024 : 16384 + (i0-16) * 1024;
        gsrc1 = (i1 < 16) ? qn + (size_t)(rowbase + i1*16 + l16) * DDIM + quad * 8
                          : pn + (size_t)(colbase + (i1-16)*16 + l16) * DDIM + quad * 8;
        ldst1 = (i1 < 16) ? i1 * 1024 : 16384 + (i1-16) * 1024;
        gsrc2 = (i2 < 16) ? qn + (size_t)(rowbase + i2*16 + l16) * DDIM + quad * 8
                          : pn + (size_t)(colbase + (i2-16)*16 + l16) * DDIM + quad * 8;
        ldst2 = (i2 < 16) ? i2 * 1024 : 16384 + (i2-16) * 1024;
    }

    f32x4 acc[4][4];
    #pragma unroll
    for (int i = 0; i < 4; ++i)
        #pragma unroll
        for (int j = 0; j < 4; ++j) acc[i][j] = (f32x4)0.0f;

    // 3 async16 per wave per STAGE -> vmcnt granularity of 3.
#define STAGE(buf, ks) do {                                             \
        unsigned char* _b = lds + (buf) * 24576;                        \
        async16(gsrc0 + (ks) * 32, _b + ldst0);                         \
        async16(gsrc1 + (ks) * 32, _b + ldst1);                         \
        async16(gsrc2 + (ks) * 32, _b + ldst2);                         \
    } while (0)

    STAGE(0, 0);
    STAGE(1, 1);
    asm volatile("s_waitcnt vmcnt(3)" ::: "memory");   // stage(0) landed
    __builtin_amdgcn_s_barrier();
    asm volatile("" ::: "memory");

    #pragma unroll
    for (int ks = 0; ks < 8; ++ks) {
        if (ks < 6) STAGE((ks + 2) % 3, ks + 2);       // issue 2 tiles ahead

        const unsigned char* ba = lds + (ks % 3) * 24576;
        bf16x8 af[4], bf[4];
        #pragma unroll
        for (int i = 0; i < 4; ++i)
            af[i] = *(const bf16x8*)(ba + (wr*4 + i) * 1024 + loff);
        #pragma unroll
        for (int j = 0; j < 4; ++j)
            bf[j] = *(const bf16x8*)(ba + 16384 + (wc*4 + j) * 1024 + loff);

        #pragma unroll
        for (int i = 0; i < 4; ++i)
            #pragma unroll
            for (int j = 0; j < 4; ++j)
                acc[i][j] = __builtin_amdgcn_mfma_f32_16x16x32_bf16(
                    af[i], bf[j], acc[i][j], 0, 0, 0);

        if (ks < 7) {
            if (ks < 6) { asm volatile("s_waitcnt vmcnt(3)" ::: "memory"); } // stage(ks+1) done
            else        { asm volatile("s_waitcnt vmcnt(0)" ::: "memory"); } // stage(7) done
            __builtin_amdgcn_s_barrier();
            asm volatile("" ::: "memory");
        }
    }
#undef STAGE

    // epilogue ------------------------------------------------------------
    __syncthreads();                   // all ds_reads done; reuse LDS
    float* red = (float*)lds;          // 2 x 256 floats: [wc][256 rows]

    #pragma unroll
    for (int i = 0; i < 4; ++i)
        #pragma unroll
        for (int r = 0; r < 4; ++r) {
            float s = __expf(acc[i][0][r] * INV_TEMP)
                    + __expf(acc[i][1][r] * INV_TEMP)
                    + __expf(acc[i][2][r] * INV_TEMP)
                    + __expf(acc[i][3][r] * INV_TEMP);
            s += __shfl_xor(s, 1);
            s += __shfl_xor(s, 2);
            s += __shfl_xor(s, 4);
            s += __shfl_xor(s, 8);
            if (l16 == 0)
                red[wc * 256 + wr * 64 + i * 16 + quad * 4 + r] = s;
        }
    __syncthreads();

    if (tid < 256)
        part[(size_t)colblk * NROWS + rowbase + tid] = red[tid] + red[256 + tid];
}

// ---------------------------------------------------------------------------
// Kernel 3: per-row total + log - diag, block partials, fused final mean via
// a 64-block completion ticket (64 agent-scope RMWs, us-scale — R6-proven).
// ---------------------------------------------------------------------------
__global__ __launch_bounds__(128) void rowsum_final_kernel(
    const float* __restrict__ part, const float* __restrict__ diag,
    float* __restrict__ loss_part, int* __restrict__ tickets,
    float* __restrict__ out)
{
    const int row = blockIdx.x * 128 + threadIdx.x;
    float s = 0.0f;
    #pragma unroll 4
    for (int cb = 0; cb < 64; ++cb)
        s += part[(size_t)cb * NROWS + row];     // coalesced across threads
    float v = logf(s) - diag[row];

    #pragma unroll
    for (int m = 1; m < 64; m <<= 1) v += __shfl_xor(v, m);
    __shared__ float wsum[2];
    __shared__ int swin;
    if ((threadIdx.x & 63) == 0) wsum[threadIdx.x >> 6] = v;
    __syncthreads();
    if (threadIdx.x == 0) {
        __hip_atomic_store(&loss_part[blockIdx.x], wsum[0] + wsum[1],
            __ATOMIC_RELEASE, __HIP_MEMORY_SCOPE_AGENT);
        swin = __hip_atomic_fetch_add(&tickets[0], 1,
                   __ATOMIC_ACQ_REL, __HIP_MEMORY_SCOPE_AGENT);
    }
    __syncthreads();
    if (swin != 63) return;            // not the last block

    if (threadIdx.x < 64) {
        float x = __hip_atomic_load(&loss_part[threadIdx.x],
                      __ATOMIC_RELAXED, __HIP_MEMORY_SCOPE_AGENT);
        #pragma unroll
        for (int m = 1; m < 64; m <<= 1) x += __shfl_xor(x, m);
        if (threadIdx.x == 0) out[0] = x * (1.0f / NROWS);
    }
}

// ---------------------------------------------------------------------------
extern "C" void kernel_launch(void* const* d_in, const int* in_sizes, int n_in,
                              void* d_out, int out_size, void* d_ws, size_t ws_size,
                              hipStream_t stream)
{
    const float* q = (const float*)d_in[0];
    const float* p = (const float*)d_in[1];

    char* ws = (char*)d_ws;
    unsigned short* qn   = (unsigned short*)ws;                          // 4 MB
    unsigned short* pn   = (unsigned short*)(ws + (size_t)NROWS*DDIM*2); // 4 MB
    float* part      = (float*)(ws + 2*(size_t)NROWS*DDIM*2);            // 2 MB
    float* diag      = part + 64 * (size_t)NROWS;                        // 32 KB
    float* loss_part = diag + NROWS;                                     // 256 B
    int*   tickets   = (int*)(loss_part + 64);

    norm_diag_kernel<<<NROWS/4, 256, 0, stream>>>(q, p, qn, pn, diag, tickets);

    simexp_kernel<<<2048, 512, 0, stream>>>(qn, pn, part);

    rowsum_final_kernel<<<64, 128, 0, stream>>>(part, diag, loss_part,
                                                tickets, (float*)d_out);
}